// Round 15
// baseline (2180.799 us; speedup 1.0000x reference)
//
#include <hip/hip_runtime.h>
#include <cstdint>

#define T_TOK 8192
#define D_DIM 1024
#define E_EXP 8
#define F_DIM 3584
#define NROW  (2 * T_TOK)      // (token, expert-slot) assignment rows
#define PROWS_PAD 18432        // expert-sorted rows padded to 256-multiples
#define MAXTILES 72            // 16384/256 + 8 experts' padding
#define MAXBANDS 18            // ceil(72/4)
#define G1_GRID (MAXBANDS * 112)          // 2016 gemm1 blocks
#define W2_ELEMS ((long)E_EXP * D_DIM * F_DIM)   // 29,360,128
#define W2_CVT_BLOCKS ((int)(W2_ELEMS / (512 * 8)))  // 7168

typedef __attribute__((ext_vector_type(8))) __bf16 bf16x8;
typedef __attribute__((ext_vector_type(4))) float f32x4;

// -------- async global->LDS: 16B/lane, LDS dest = wave-uniform base + lane*16 --------
__device__ __forceinline__ void gload16(const void* g, void* l) {
    __builtin_amdgcn_global_load_lds(
        (const __attribute__((address_space(1))) void*)(g),
        (__attribute__((address_space(3))) void*)(l),
        16, 0, 0);
}

// -------- fp32 -> bf16 conversion (8 elems/thread) --------
__device__ __forceinline__ void cvt8(const float* __restrict__ in, __bf16* __restrict__ out, long i) {
    const float4 f0 = *(const float4*)(in + i);
    const float4 f1 = *(const float4*)(in + i + 4);
    bf16x8 o;
    o[0] = (__bf16)f0.x; o[1] = (__bf16)f0.y; o[2] = (__bf16)f0.z; o[3] = (__bf16)f0.w;
    o[4] = (__bf16)f1.x; o[5] = (__bf16)f1.y; o[6] = (__bf16)f1.z; o[7] = (__bf16)f1.w;
    *(bf16x8*)(out + i) = o;
}

// merged dual-source cvt: blocks [0, nb) -> in0/out0, [nb, 2nb) -> in1/out1
__global__ void cvt2_kernel(const float* __restrict__ in0, __bf16* __restrict__ out0,
                            const float* __restrict__ in1, __bf16* __restrict__ out1,
                            long n, int nb) {
    const int b = blockIdx.x;
    const float* in = (b < nb) ? in0 : in1;
    __bf16* out = (b < nb) ? out0 : out1;
    const long i = ((long)(b < nb ? b : b - nb) * blockDim.x + threadIdx.x) * 8;
    if (i < n) cvt8(in, out, i);
}

// -------- routing --------
__global__ void route_kernel(const float* __restrict__ rl, int* cnt,
                             int* __restrict__ eidx, float* __restrict__ ewgt) {
    int t = blockIdx.x * blockDim.x + threadIdx.x;
    if (t >= T_TOK) return;
    float l[8];
#pragma unroll
    for (int e = 0; e < 8; ++e) l[e] = rl[t * 8 + e];
    int i0 = 0; float v0 = l[0];
    int i1 = -1; float v1 = -1e30f;
#pragma unroll
    for (int e = 1; e < 8; ++e) {
        if (l[e] > v0) { v1 = v0; i1 = i0; v0 = l[e]; i0 = e; }
        else if (l[e] > v1) { v1 = l[e]; i1 = e; }
    }
    float wsec = 1.f / (1.f + __expf(v0 - v1));
    eidx[2 * t] = i0; eidx[2 * t + 1] = i1;
    ewgt[2 * t] = 1.f - wsec; ewgt[2 * t + 1] = wsec;
    atomicAdd(&cnt[i0], 1); atomicAdd(&cnt[i1], 1);
}

// scan: 256-padded per-expert offsets
__global__ void scan_kernel(const int* __restrict__ cnt, int* __restrict__ pofs) {
    if (threadIdx.x == 0) {
        int a = 0;
        for (int e = 0; e < E_EXP; ++e) { pofs[e] = a; a += (cnt[e] + 255) & ~255; }
        pofs[E_EXP] = a;
    }
}

// compact live M-tile table: (expert, row0) per 256-row tile + count
__global__ void tiles_kernel(const int* __restrict__ pofs, int* __restrict__ tile_e,
                             int* __restrict__ tile_r0, int* __restrict__ meta) {
    if (threadIdx.x == 0) {
        int n = 0;
        for (int e = 0; e < E_EXP; ++e)
            for (int r = pofs[e]; r < pofs[e + 1]; r += 256) {
                tile_e[n] = e; tile_r0[n] = r; ++n;
            }
        meta[0] = n;
    }
}

__global__ void assign_kernel(const int* __restrict__ eidx, const int* __restrict__ pofs,
                              int* cnt2, int* __restrict__ tokOf, int* __restrict__ rowOf) {
    int t = blockIdx.x * blockDim.x + threadIdx.x;
    if (t >= T_TOK) return;
#pragma unroll
    for (int s = 0; s < 2; ++s) {
        int e = eidx[2 * t + s];
        int pos = atomicAdd(&cnt2[e], 1);
        int prow = pofs[e] + pos;
        tokOf[prow] = t;
        rowOf[2 * t + s] = prow;
    }
}

// gather + cvt: xg[prow] = bf16(x[tokOf[prow]]); pad rows (tokOf=-1) -> 0
__global__ void gather_kernel(const float* __restrict__ x, const int* __restrict__ tokOf,
                              __bf16* __restrict__ xg) {
    const int idx = blockIdx.x * blockDim.x + threadIdx.x;   // PROWS_PAD * 128
    const int pr = idx >> 7;
    const int j = (idx & 127) * 8;
    const int tk = tokOf[pr];
    bf16x8 o = {};
    if (tk >= 0) {
        const float4 f0 = *(const float4*)(x + (long)tk * D_DIM + j);
        const float4 f1 = *(const float4*)(x + (long)tk * D_DIM + j + 4);
        o[0] = (__bf16)f0.x; o[1] = (__bf16)f0.y; o[2] = (__bf16)f0.z; o[3] = (__bf16)f0.w;
        o[4] = (__bf16)f1.x; o[5] = (__bf16)f1.y; o[6] = (__bf16)f1.z; o[7] = (__bf16)f1.w;
    }
    *(bf16x8*)(xg + (long)pr * D_DIM + j) = o;
}

// ---- chunk mapping for a 128x64 bf16 half-tile (16KB), st_16x32-swizzled ----
__device__ __forceinline__ int chunk_row(int c) { return ((c >> 7) << 4) | ((c >> 2) & 15); }
__device__ __forceinline__ int chunk_col(int c) {
    return ((c >> 6) & 1) * 32 + (((c & 3) * 8) ^ (((c >> 5) & 1) << 4));
}

// ---- chunk mapping for a 256x32 bf16 tile (16KB), same swizzle family ----
// group g = 16 rows x 32 cols (512 elems); within: row fr, 16B slot
// slotswz = slot ^ (fr>=8 ? 2 : 0).
__device__ __forceinline__ int chunk32_row(int c) { return ((c >> 6) << 4) | ((c >> 2) & 15); }
__device__ __forceinline__ int chunk32_col(int c) {
    return ((c & 3) ^ (((c >> 5) & 1) << 1)) * 8;
}

// =========================================================================
// R9 pipeline (gemm1; best measured 293us / MfmaUtil 38.1 / conflicts 0).
// =========================================================================
template <int NT>
__device__ __forceinline__ void moe_pipeline(
    const __bf16* const (&srcA)[2][2], const __bf16* const (&srcB)[2][2],
    __bf16 (&Ash)[2][2][8192], __bf16 (&Bsh)[2][2][8192],
    int wave, int abase, int wm, int bh, int bsel, f32x4 (&acc)[8][4])
{
    auto stA = [&](int buf, int kt, int h) {
        const long k0 = (long)kt * 64;
        gload16(srcA[h][0] + k0, &Ash[buf][h][(0 * 512 + wave * 64) * 8]);
        gload16(srcA[h][1] + k0, &Ash[buf][h][(1 * 512 + wave * 64) * 8]);
    };
    auto stB = [&](int buf, int kt, int h) {
        const long k0 = (long)kt * 64;
        gload16(srcB[h][0] + k0, &Bsh[buf][h][(0 * 512 + wave * 64) * 8]);
        gload16(srcB[h][1] + k0, &Bsh[buf][h][(1 * 512 + wave * 64) * 8]);
    };

    bf16x8 bfr[4][2];
    bf16x8 afr[4][2];
    bf16x8 afr2[4][2];

#define LD_A4(dst, Ab, h) \
    _Pragma("unroll") for (int j = 0; j < 4; ++j) { \
        dst[j][0] = *(const bf16x8*)((Ab) + ((4*(h)+j) * 2 + 0) * 512); \
        dst[j][1] = *(const bf16x8*)((Ab) + ((4*(h)+j) * 2 + 1) * 512); \
    }

#define LD_B(Bb) \
    _Pragma("unroll") for (int ni = 0; ni < 4; ++ni) { \
        bfr[ni][0] = *(const bf16x8*)((Bb) + ((bsel * 4 + ni) * 2 + 0) * 512); \
        bfr[ni][1] = *(const bf16x8*)((Bb) + ((bsel * 4 + ni) * 2 + 1) * 512); \
    }

#define MFMA_H(h, src) \
    _Pragma("unroll") for (int j = 0; j < 4; ++j) \
        _Pragma("unroll") for (int ni = 0; ni < 4; ++ni) { \
            acc[4*(h)+j][ni] = __builtin_amdgcn_mfma_f32_16x16x32_bf16(src[j][0], bfr[ni][0], acc[4*(h)+j][ni], 0, 0, 0); \
            acc[4*(h)+j][ni] = __builtin_amdgcn_mfma_f32_16x16x32_bf16(src[j][1], bfr[ni][1], acc[4*(h)+j][ni], 0, 0, 0); \
        }

#define PH_OPEN() \
    __builtin_amdgcn_sched_barrier(0); \
    __builtin_amdgcn_s_barrier(); \
    asm volatile("s_waitcnt lgkmcnt(0)" ::: "memory"); \
    __builtin_amdgcn_sched_barrier(0); \
    __builtin_amdgcn_s_setprio(1);

#define PH_CLOSE() \
    __builtin_amdgcn_s_setprio(0); \
    __builtin_amdgcn_sched_barrier(0); \
    __builtin_amdgcn_s_barrier(); \
    __builtin_amdgcn_sched_barrier(0);

#define PH_CLOSE_G(lastf) \
    __builtin_amdgcn_s_setprio(0); \
    __builtin_amdgcn_sched_barrier(0); \
    if (lastf) { asm volatile("s_waitcnt vmcnt(0)" ::: "memory"); } \
    else       { asm volatile("s_waitcnt vmcnt(4)" ::: "memory"); } \
    __builtin_amdgcn_s_barrier(); \
    __builtin_amdgcn_sched_barrier(0);

    stA(0, 0, 0); stA(0, 0, 1); stB(0, 0, 0); stB(0, 0, 1);
    stB(1, 1, 0); stB(1, 1, 1);
    asm volatile("s_waitcnt vmcnt(4)" ::: "memory");
    __builtin_amdgcn_s_barrier();

    const __bf16* AbE = &Ash[0][wm][abase];
    const __bf16* BbE = &Bsh[0][bh][abase];
    const __bf16* AbO = &Ash[1][wm][abase];
    const __bf16* BbO = &Bsh[1][bh][abase];

    for (int it = 0; it < NT / 2; ++it) {
        const int kv = 2 * it + 1;
        const bool last = (it == NT / 2 - 1);
        LD_A4(afr, AbE, 0) LD_B(BbE)
        stA(1, kv, 0); stA(1, kv, 1);
        PH_OPEN()
        MFMA_H(0, afr)
        LD_A4(afr2, AbE, 1)
        PH_CLOSE()
        if (!last) { stB(0, kv + 1, 0); stB(0, kv + 1, 1); }
        PH_OPEN()
        MFMA_H(1, afr2)
        PH_CLOSE_G(last)
        LD_A4(afr, AbO, 0) LD_B(BbO)
        if (!last) { stA(0, kv + 1, 0); stA(0, kv + 1, 1); }
        PH_OPEN()
        MFMA_H(0, afr)
        LD_A4(afr2, AbO, 1)
        PH_CLOSE()
        if (!last) { stB(1, kv + 2, 0); stB(1, kv + 2, 1); }
        PH_OPEN()
        MFMA_H(1, afr2)
        PH_CLOSE_G(last)
    }
#undef LD_A4
#undef LD_B
#undef MFMA_H
#undef PH_OPEN
#undef PH_CLOSE
#undef PH_CLOSE_G
}

// =========================================================================
// GEMM1 (+ fused w2 cvt tail blocks) — R14 exact.
// =========================================================================
__global__ __launch_bounds__(512, 1)
void gemm1_kernel(const __bf16* __restrict__ xg,
                  const __bf16* __restrict__ w1b,
                  const __bf16* __restrict__ w3b,
                  const int* __restrict__ tile_e,
                  const int* __restrict__ tile_r0,
                  const int* __restrict__ meta,
                  __bf16* __restrict__ h,
                  const float* __restrict__ w2src,
                  __bf16* __restrict__ w2dst) {
    const int bid = blockIdx.x;
    if (bid >= G1_GRID) {
        const long i = ((long)(bid - G1_GRID) * 512 + threadIdx.x) * 8;
        if (i < W2_ELEMS) cvt8(w2src, w2dst, i);
        return;
    }
    const int count = meta[0];
    const int bands = (count + 3) >> 2;
    const int live = bands * 112;
    if (bid >= live) return;
    const int w = (bid & 7) * (live >> 3) + (bid >> 3);
    const int q28 = w / 28, r = w % 28;
    const int tile = (q28 >> 2) * 4 + r / 7;
    const int nt = (q28 & 3) * 7 + r % 7;
    if (tile >= count) return;
    const int e = tile_e[tile];
    const int row0 = tile_r0[tile];

    __shared__ __align__(16) __bf16 Ash[2][2][8192];
    __shared__ __align__(16) __bf16 Bsh[2][2][8192];

    const int tid = threadIdx.x;
    const int wave = tid >> 6, lane = tid & 63;
    const int wm = wave >> 2, wn = wave & 3;
    const int fr = lane & 15, fg = lane >> 4;

    const __bf16* srcA[2][2];
    const __bf16* srcB[2][2];
#pragma unroll
    for (int half = 0; half < 2; ++half)
#pragma unroll
        for (int j = 0; j < 2; ++j) {
            const int c = tid + j * 512;
            srcA[half][j] = xg + (long)(row0 + half * 128 + chunk_row(c)) * D_DIM + chunk_col(c);
            const int rb = half * 128 + chunk_row(c);
            const int blk = rb >> 4;
            const int f = nt * 128 + (blk >> 1) * 16 + (rb & 15);
            srcB[half][j] = ((blk & 1) ? w3b : w1b) + ((long)e * F_DIM + f) * D_DIM + chunk_col(c);
        }

    const int abase = fr * 32 + ((fg * 8) ^ ((fr & 8) << 1));
    f32x4 acc[8][4] = {};

    moe_pipeline<16>(srcA, srcB, Ash, Bsh, wave, abase, wm, wn >> 1, wn & 1, acc);

#pragma unroll
    for (int mi = 0; mi < 8; ++mi) {
#pragma unroll
        for (int reg = 0; reg < 4; ++reg) {
            const int lm = wm * 128 + mi * 16 + fg * 4 + reg;
            const long hrow = (long)(row0 + lm) * F_DIM;
#pragma unroll
            for (int b = 0; b < 2; ++b) {
                const float g = acc[mi][2 * b][reg];
                const float u = acc[mi][2 * b + 1][reg];
                const float s = g / (1.f + __expf(-g));
                h[hrow + nt * 128 + (wn * 2 + b) * 16 + fr] = (__bf16)(s * u);
            }
        }
    }
}

// =========================================================================
// GEMM2 (R15): 256x256 tile, BK=32, 64 KB LDS -> 2 blocks/CU co-resident.
// No split-K (NT=112, 4 nt tiles of 256 cols) -> no partials, 288 blocks all
// resident. 1 barrier/K-tile; stage(t+1 -> buf[cur^1]) issued after the open
// barrier (all waves' reads of tile t-1 from buf[cur^1] provably drained);
// vmcnt(0) gate waits exactly the 4 outstanding loads of buf[cur].
// Cross-block wave overlap (m97 mechanism) hides the shallow-gate stall.
// =========================================================================
__global__ __launch_bounds__(512, 4)
void gemm2_kernel(const __bf16* __restrict__ hb,
                  const __bf16* __restrict__ w2b,
                  const int* __restrict__ tile_e,
                  const int* __restrict__ tile_r0,
                  const int* __restrict__ meta,
                  __bf16* __restrict__ o2) {
    const int count = meta[0];
    const int live = (count * 4 + 7) & ~7;
    const int bid = blockIdx.x;
    if (bid >= live) return;
    const int w = (bid & 7) * (live >> 3) + (bid >> 3);   // XCD-chunked
    const int tile = w >> 2, nt = w & 3;
    if (tile >= count) return;
    const int e = tile_e[tile];
    const int row0 = tile_r0[tile];

    __shared__ __align__(16) __bf16 Ash[2][8192];   // 2 x 16 KB (256x32)
    __shared__ __align__(16) __bf16 Bsh[2][8192];   // 2 x 16 KB

    const int tid = threadIdx.x;
    const int wave = tid >> 6, lane = tid & 63;
    const int wm = wave >> 2, wn = wave & 3;        // 2m x 4n over 256x256
    const int fr = lane & 15, fg = lane >> 4;

    // staging: 2 A-chunks + 2 B-chunks per thread per K-tile (16B each)
    const __bf16* srcA[2];
    const __bf16* srcB[2];
#pragma unroll
    for (int j = 0; j < 2; ++j) {
        const int c = tid + j * 512;
        srcA[j] = hb + (long)(row0 + chunk32_row(c)) * F_DIM + chunk32_col(c);
        srcB[j] = w2b + ((long)e * D_DIM + nt * 256 + chunk32_row(c)) * F_DIM + chunk32_col(c);
    }

    auto stage = [&](int buf, int kt) {
        const long k0 = (long)kt * 32;
        gload16(srcA[0] + k0, &Ash[buf][(tid) * 8]);
        gload16(srcA[1] + k0, &Ash[buf][(tid + 512) * 8]);
        gload16(srcB[0] + k0, &Bsh[buf][(tid) * 8]);
        gload16(srcB[1] + k0, &Bsh[buf][(tid + 512) * 8]);
    };

    const int foff = fr * 32 + ((fg * 8) ^ ((fr & 8) << 1));   // within 16x32 group
    f32x4 acc[8][4] = {};

    stage(0, 0);
    const int NT = F_DIM / 32;   // 112
    for (int t = 0; t < NT; ++t) {
        const int cur = t & 1;
        __builtin_amdgcn_sched_barrier(0);
        asm volatile("s_waitcnt vmcnt(0)" ::: "memory");   // buf[cur] landed
        __builtin_amdgcn_s_barrier();
        __builtin_amdgcn_sched_barrier(0);
        if (t + 1 < NT) stage(cur ^ 1, t + 1);
        bf16x8 af[8], bf[4];
#pragma unroll
        for (int mi = 0; mi < 8; ++mi)
            af[mi] = *(const bf16x8*)(&Ash[cur][(wm * 8 + mi) * 512 + foff]);
#pragma unroll
        for (int ni = 0; ni < 4; ++ni)
            bf[ni] = *(const bf16x8*)(&Bsh[cur][(wn * 4 + ni) * 512 + foff]);
        asm volatile("s_waitcnt lgkmcnt(0)" ::: "memory");
        __builtin_amdgcn_sched_barrier(0);
        __builtin_amdgcn_s_setprio(1);
#pragma unroll
        for (int mi = 0; mi < 8; ++mi)
#pragma unroll
            for (int ni = 0; ni < 4; ++ni)
                acc[mi][ni] = __builtin_amdgcn_mfma_f32_16x16x32_bf16(af[mi], bf[ni], acc[mi][ni], 0, 0, 0);
        __builtin_amdgcn_s_setprio(0);
        __builtin_amdgcn_sched_barrier(0);
    }
    asm volatile("s_waitcnt vmcnt(0)" ::: "memory");

    // epilogue: o2[row, d] (single set, no partials)
#pragma unroll
    for (int mi = 0; mi < 8; ++mi) {
#pragma unroll
        for (int reg = 0; reg < 4; ++reg) {
            const int lm = wm * 128 + mi * 16 + fg * 4 + reg;
            const long obase = (long)(row0 + lm) * D_DIM + nt * 256 + wn * 64 + fr;
#pragma unroll
            for (int ni = 0; ni < 4; ++ni)
                o2[obase + ni * 16] = (__bf16)acc[mi][ni][reg];
        }
    }
}

// -------- combine: out[t] = w0*o2[r0] + w1*o2[r1] --------
__global__ void combine_kernel(const __bf16* __restrict__ o2, const int* __restrict__ rowOf,
                               const float* __restrict__ ewgt, float* __restrict__ out) {
    const int idx = blockIdx.x * blockDim.x + threadIdx.x;  // T * D/8
    const int t = idx >> 7;
    const int j = (idx & 127) * 8;
    const long r0 = rowOf[2 * t], r1 = rowOf[2 * t + 1];
    const float w0 = ewgt[2 * t], w1 = ewgt[2 * t + 1];
    const bf16x8 a = *(const bf16x8*)(o2 + r0 * D_DIM + j);
    const bf16x8 b = *(const bf16x8*)(o2 + r1 * D_DIM + j);
    float r[8];
#pragma unroll
    for (int q = 0; q < 8; ++q) r[q] = w0 * (float)a[q] + w1 * (float)b[q];
    float4* ob = (float4*)(out + (long)t * D_DIM + j);
    ob[0] = make_float4(r[0], r[1], r[2], r[3]);
    ob[1] = make_float4(r[4], r[5], r[6], r[7]);
}

// =========================================================================
extern "C" void kernel_launch(void* const* d_in, const int* in_sizes, int n_in,
                              void* d_out, int out_size, void* d_ws, size_t ws_size,
                              hipStream_t stream) {
    const float* x  = (const float*)d_in[0];
    const float* w1 = (const float*)d_in[1];
    const float* w3 = (const float*)d_in[2];
    const float* w2 = (const float*)d_in[3];
    const float* rl = (const float*)d_in[4];
    float* out = (float*)d_out;

    char* ws = (char*)d_ws;
    size_t off = 0;
    auto alloc = [&](size_t bytes) {
        void* p = ws + off;
        off += (bytes + 255) & ~(size_t)255;
        return p;
    };
    __bf16* xg   = (__bf16*)alloc((size_t)PROWS_PAD * D_DIM * 2);        // 37.7 MB
    __bf16* w1b  = (__bf16*)alloc((size_t)E_EXP * F_DIM * D_DIM * 2);    // 58.7 MB
    __bf16* w3b  = (__bf16*)alloc((size_t)E_EXP * F_DIM * D_DIM * 2);    // 58.7 MB
    __bf16* hbuf = (__bf16*)alloc((size_t)PROWS_PAD * F_DIM * 2);        // 132.1 MB
    int*   tokOf = (int*)alloc(PROWS_PAD * 4);
    int*   rowOf = (int*)alloc(NROW * 4);
    int*   eidx  = (int*)alloc(NROW * 4);
    float* ewgt  = (float*)alloc(NROW * 4);
    int*   cnt1  = (int*)alloc(64);
    int*   cnt2  = (int*)alloc(64);
    int*   pofs  = (int*)alloc(64);
    int*   tileE = (int*)alloc(MAXTILES * 4 + 64);
    int*   tileR = (int*)alloc(MAXTILES * 4 + 64);
    int*   meta  = (int*)alloc(64);

    const size_t W2B_BYTES = (size_t)W2_ELEMS * 2;                       // 58.7 MB
    const size_t front = off;
    // Fused path: w2b fresh & disjoint -> w2 cvt as gemm1 tail blocks.
    // o2 (37.7 MB) aliases dead xg. Fallback: R9-style serial layout.
    const bool fused = (ws_size >= front + W2B_BYTES);
    __bf16* w2b;
    __bf16* o2;
    if (fused) {
        w2b = (__bf16*)alloc(W2B_BYTES);
        o2 = (__bf16*)ws;                           // over dead xg
    } else {
        w2b = (__bf16*)ws;                          // over dead xg+w1b-prefix
        o2 = (__bf16*)(ws + W2B_BYTES);             // over dead w1b-tail+w3b
    }

    hipMemsetAsync(cnt1, 0, 64, stream);
    hipMemsetAsync(cnt2, 0, 64, stream);
    hipMemsetAsync(tokOf, 0xFF, PROWS_PAD * 4, stream);

    route_kernel<<<T_TOK / 256, 256, 0, stream>>>(rl, cnt1, eidx, ewgt);
    scan_kernel<<<1, 64, 0, stream>>>(cnt1, pofs);
    tiles_kernel<<<1, 64, 0, stream>>>(pofs, tileE, tileR, meta);
    assign_kernel<<<T_TOK / 256, 256, 0, stream>>>(eidx, pofs, cnt2, tokOf, rowOf);
    gather_kernel<<<PROWS_PAD * 128 / 256, 256, 0, stream>>>(x, tokOf, xg);

    {   // merged w1+w3 cvt (one launch)
        const long n = (long)E_EXP * F_DIM * D_DIM;
        const int nb = (int)(n / 8 / 256);
        cvt2_kernel<<<2 * nb, 256, 0, stream>>>(w1, w1b, w3, w3b, n, nb);
    }

    if (fused) {
        gemm1_kernel<<<G1_GRID + W2_CVT_BLOCKS, 512, 0, stream>>>(
            xg, w1b, w3b, tileE, tileR, meta, hbuf, w2, w2b);
    } else {
        gemm1_kernel<<<G1_GRID, 512, 0, stream>>>(
            xg, w1b, w3b, tileE, tileR, meta, hbuf, w2, w2b);
        const long n = W2_ELEMS;
        cvt2_kernel<<<(int)(n / 8 / 256), 256, 0, stream>>>(w2, w2b, w2, w2b, n, (int)(n / 8 / 256));
    }

    gemm2_kernel<<<MAXTILES * 4, 512, 0, stream>>>(hbuf, w2b, tileE, tileR, meta, o2);

    combine_kernel<<<T_TOK * (D_DIM / 8) / 256, 256, 0, stream>>>(o2, rowOf, ewgt, out);
}

// Round 16
// 650.694 us; speedup vs baseline: 3.3515x; 3.3515x over previous
//
#include <hip/hip_runtime.h>
#include <cstdint>

#define T_TOK 8192
#define D_DIM 1024
#define E_EXP 8
#define F_DIM 3584
#define NROW  (2 * T_TOK)      // (token, expert-slot) assignment rows
#define PROWS_PAD 18432        // expert-sorted rows padded to 256-multiples
#define MAXTILES 72            // 16384/256 + 8 experts' padding
#define MAXBANDS 18            // ceil(72/4)
#define G1_GRID (MAXBANDS * 112)          // 2016 gemm1 blocks
#define W2_ELEMS ((long)E_EXP * D_DIM * F_DIM)   // 29,360,128
#define W2_CVT_BLOCKS ((int)(W2_ELEMS / (512 * 8)))  // 7168
#define W13_ELEMS ((long)E_EXP * F_DIM * D_DIM)
#define GATH_BLOCKS (PROWS_PAD * 128 / 256)          // 9216
#define W13_BLOCKS ((int)(W13_ELEMS / 8 / 256))      // 14336

typedef __attribute__((ext_vector_type(8))) __bf16 bf16x8;
typedef __attribute__((ext_vector_type(4))) float f32x4;

// -------- async global->LDS: 16B/lane, LDS dest = wave-uniform base + lane*16 --------
__device__ __forceinline__ void gload16(const void* g, void* l) {
    __builtin_amdgcn_global_load_lds(
        (const __attribute__((address_space(1))) void*)(g),
        (__attribute__((address_space(3))) void*)(l),
        16, 0, 0);
}

// -------- fp32 -> bf16 conversion (8 elems/thread) --------
__device__ __forceinline__ void cvt8(const float* __restrict__ in, __bf16* __restrict__ out, long i) {
    const float4 f0 = *(const float4*)(in + i);
    const float4 f1 = *(const float4*)(in + i + 4);
    bf16x8 o;
    o[0] = (__bf16)f0.x; o[1] = (__bf16)f0.y; o[2] = (__bf16)f0.z; o[3] = (__bf16)f0.w;
    o[4] = (__bf16)f1.x; o[5] = (__bf16)f1.y; o[6] = (__bf16)f1.z; o[7] = (__bf16)f1.w;
    *(bf16x8*)(out + i) = o;
}

__global__ void cvt_kernel(const float* __restrict__ in, __bf16* __restrict__ out, long n) {
    long i = ((long)blockIdx.x * blockDim.x + threadIdx.x) * 8;
    if (i >= n) return;
    cvt8(in, out, i);
}

// -------- merged prep: x gather+cvt, w1 cvt, w3 cvt in one launch --------
__global__ void prep_kernel(const float* __restrict__ x, const int* __restrict__ tokOf,
                            __bf16* __restrict__ xg,
                            const float* __restrict__ w1, __bf16* __restrict__ w1b,
                            const float* __restrict__ w3, __bf16* __restrict__ w3b) {
    const int b = blockIdx.x;
    if (b < GATH_BLOCKS) {
        const int idx = b * 256 + threadIdx.x;      // PROWS_PAD * 128
        const int pr = idx >> 7;
        const int j = (idx & 127) * 8;
        const int tk = tokOf[pr];
        bf16x8 o = {};
        if (tk >= 0) {
            const float4 f0 = *(const float4*)(x + (long)tk * D_DIM + j);
            const float4 f1 = *(const float4*)(x + (long)tk * D_DIM + j + 4);
            o[0] = (__bf16)f0.x; o[1] = (__bf16)f0.y; o[2] = (__bf16)f0.z; o[3] = (__bf16)f0.w;
            o[4] = (__bf16)f1.x; o[5] = (__bf16)f1.y; o[6] = (__bf16)f1.z; o[7] = (__bf16)f1.w;
        }
        *(bf16x8*)(xg + (long)pr * D_DIM + j) = o;
    } else if (b < GATH_BLOCKS + W13_BLOCKS) {
        const long i = ((long)(b - GATH_BLOCKS) * 256 + threadIdx.x) * 8;
        if (i < W13_ELEMS) cvt8(w1, w1b, i);
    } else {
        const long i = ((long)(b - GATH_BLOCKS - W13_BLOCKS) * 256 + threadIdx.x) * 8;
        if (i < W13_ELEMS) cvt8(w3, w3b, i);
    }
}

// -------- routing --------
__global__ void route_kernel(const float* __restrict__ rl, int* cnt,
                             int* __restrict__ eidx, float* __restrict__ ewgt) {
    int t = blockIdx.x * blockDim.x + threadIdx.x;
    if (t >= T_TOK) return;
    float l[8];
#pragma unroll
    for (int e = 0; e < 8; ++e) l[e] = rl[t * 8 + e];
    int i0 = 0; float v0 = l[0];
    int i1 = -1; float v1 = -1e30f;
#pragma unroll
    for (int e = 1; e < 8; ++e) {
        if (l[e] > v0) { v1 = v0; i1 = i0; v0 = l[e]; i0 = e; }
        else if (l[e] > v1) { v1 = l[e]; i1 = e; }
    }
    float wsec = 1.f / (1.f + __expf(v0 - v1));
    eidx[2 * t] = i0; eidx[2 * t + 1] = i1;
    ewgt[2 * t] = 1.f - wsec; ewgt[2 * t + 1] = wsec;
    atomicAdd(&cnt[i0], 1); atomicAdd(&cnt[i1], 1);
}

// scan: 256-padded per-expert offsets
__global__ void scan_kernel(const int* __restrict__ cnt, int* __restrict__ pofs) {
    if (threadIdx.x == 0) {
        int a = 0;
        for (int e = 0; e < E_EXP; ++e) { pofs[e] = a; a += (cnt[e] + 255) & ~255; }
        pofs[E_EXP] = a;
    }
}

// compact live M-tile table: (expert, row0) per 256-row tile + count
__global__ void tiles_kernel(const int* __restrict__ pofs, int* __restrict__ tile_e,
                             int* __restrict__ tile_r0, int* __restrict__ meta) {
    if (threadIdx.x == 0) {
        int n = 0;
        for (int e = 0; e < E_EXP; ++e)
            for (int r = pofs[e]; r < pofs[e + 1]; r += 256) {
                tile_e[n] = e; tile_r0[n] = r; ++n;
            }
        meta[0] = n;
    }
}

__global__ void assign_kernel(const int* __restrict__ eidx, const int* __restrict__ pofs,
                              int* cnt2, int* __restrict__ tokOf, int* __restrict__ rowOf) {
    int t = blockIdx.x * blockDim.x + threadIdx.x;
    if (t >= T_TOK) return;
#pragma unroll
    for (int s = 0; s < 2; ++s) {
        int e = eidx[2 * t + s];
        int pos = atomicAdd(&cnt2[e], 1);
        int prow = pofs[e] + pos;
        tokOf[prow] = t;
        rowOf[2 * t + s] = prow;
    }
}

// ---- chunk mapping for a 128x64 bf16 half-tile (16KB), st_16x32-swizzled ----
__device__ __forceinline__ int chunk_row(int c) { return ((c >> 7) << 4) | ((c >> 2) & 15); }
__device__ __forceinline__ int chunk_col(int c) {
    return ((c >> 6) & 1) * 32 + (((c & 3) * 8) ^ (((c >> 5) & 1) << 4));
}

// =========================================================================
// R9 pipeline (best measured: gemm1 293us / MfmaUtil 38.1 / conflicts 0).
// 4-phase schedule + latency-hoisted second A-read. Per 2 K-tiles:
//   E0: [ldA mi0-3(u)+ldB(u)] stage A(v) -> MFMA mi0-3 ++ ldA mi4-7(u)
//   E1: stage B(u+2) -> MFMA mi4-7                     [vmcnt(4) gate]
//   O0: [ldA mi0-3(v)+ldB(v)] stage A(u+2) -> MFMA mi0-3 ++ ldA mi4-7(v)
//   O1: stage B(v+2) -> MFMA mi4-7                     [vmcnt(4) gate]
// =========================================================================
template <int NT>
__device__ __forceinline__ void moe_pipeline(
    const __bf16* const (&srcA)[2][2], const __bf16* const (&srcB)[2][2],
    __bf16 (&Ash)[2][2][8192], __bf16 (&Bsh)[2][2][8192],
    int wave, int abase, int wm, int bh, int bsel, f32x4 (&acc)[8][4])
{
    auto stA = [&](int buf, int kt, int h) {
        const long k0 = (long)kt * 64;
        gload16(srcA[h][0] + k0, &Ash[buf][h][(0 * 512 + wave * 64) * 8]);
        gload16(srcA[h][1] + k0, &Ash[buf][h][(1 * 512 + wave * 64) * 8]);
    };
    auto stB = [&](int buf, int kt, int h) {
        const long k0 = (long)kt * 64;
        gload16(srcB[h][0] + k0, &Bsh[buf][h][(0 * 512 + wave * 64) * 8]);
        gload16(srcB[h][1] + k0, &Bsh[buf][h][(1 * 512 + wave * 64) * 8]);
    };

    bf16x8 bfr[4][2];
    bf16x8 afr[4][2];    // mi 0-3 fragments
    bf16x8 afr2[4][2];   // mi 4-7 fragments (loaded under the mi0-3 MFMA cluster)

#define LD_A4(dst, Ab, h) \
    _Pragma("unroll") for (int j = 0; j < 4; ++j) { \
        dst[j][0] = *(const bf16x8*)((Ab) + ((4*(h)+j) * 2 + 0) * 512); \
        dst[j][1] = *(const bf16x8*)((Ab) + ((4*(h)+j) * 2 + 1) * 512); \
    }

#define LD_B(Bb) \
    _Pragma("unroll") for (int ni = 0; ni < 4; ++ni) { \
        bfr[ni][0] = *(const bf16x8*)((Bb) + ((bsel * 4 + ni) * 2 + 0) * 512); \
        bfr[ni][1] = *(const bf16x8*)((Bb) + ((bsel * 4 + ni) * 2 + 1) * 512); \
    }

#define MFMA_H(h, src) \
    _Pragma("unroll") for (int j = 0; j < 4; ++j) \
        _Pragma("unroll") for (int ni = 0; ni < 4; ++ni) { \
            acc[4*(h)+j][ni] = __builtin_amdgcn_mfma_f32_16x16x32_bf16(src[j][0], bfr[ni][0], acc[4*(h)+j][ni], 0, 0, 0); \
            acc[4*(h)+j][ni] = __builtin_amdgcn_mfma_f32_16x16x32_bf16(src[j][1], bfr[ni][1], acc[4*(h)+j][ni], 0, 0, 0); \
        }

#define PH_OPEN() \
    __builtin_amdgcn_sched_barrier(0); \
    __builtin_amdgcn_s_barrier(); \
    asm volatile("s_waitcnt lgkmcnt(0)" ::: "memory"); \
    __builtin_amdgcn_sched_barrier(0); \
    __builtin_amdgcn_s_setprio(1);

#define PH_CLOSE() \
    __builtin_amdgcn_s_setprio(0); \
    __builtin_amdgcn_sched_barrier(0); \
    __builtin_amdgcn_s_barrier(); \
    __builtin_amdgcn_sched_barrier(0);

#define PH_CLOSE_G(lastf) \
    __builtin_amdgcn_s_setprio(0); \
    __builtin_amdgcn_sched_barrier(0); \
    if (lastf) { asm volatile("s_waitcnt vmcnt(0)" ::: "memory"); } \
    else       { asm volatile("s_waitcnt vmcnt(4)" ::: "memory"); } \
    __builtin_amdgcn_s_barrier(); \
    __builtin_amdgcn_sched_barrier(0);

    stA(0, 0, 0); stA(0, 0, 1); stB(0, 0, 0); stB(0, 0, 1);
    stB(1, 1, 0); stB(1, 1, 1);
    asm volatile("s_waitcnt vmcnt(4)" ::: "memory");
    __builtin_amdgcn_s_barrier();

    const __bf16* AbE = &Ash[0][wm][abase];
    const __bf16* BbE = &Bsh[0][bh][abase];
    const __bf16* AbO = &Ash[1][wm][abase];
    const __bf16* BbO = &Bsh[1][bh][abase];

    for (int it = 0; it < NT / 2; ++it) {
        const int kv = 2 * it + 1;
        const bool last = (it == NT / 2 - 1);
        LD_A4(afr, AbE, 0) LD_B(BbE)
        stA(1, kv, 0); stA(1, kv, 1);
        PH_OPEN()
        MFMA_H(0, afr)
        LD_A4(afr2, AbE, 1)
        PH_CLOSE()
        if (!last) { stB(0, kv + 1, 0); stB(0, kv + 1, 1); }
        PH_OPEN()
        MFMA_H(1, afr2)
        PH_CLOSE_G(last)
        LD_A4(afr, AbO, 0) LD_B(BbO)
        if (!last) { stA(0, kv + 1, 0); stA(0, kv + 1, 1); }
        PH_OPEN()
        MFMA_H(0, afr)
        LD_A4(afr2, AbO, 1)
        PH_CLOSE()
        if (!last) { stB(1, kv + 2, 0); stB(1, kv + 2, 1); }
        PH_OPEN()
        MFMA_H(1, afr2)
        PH_CLOSE_G(last)
    }
#undef LD_A4
#undef LD_B
#undef MFMA_H
#undef PH_OPEN
#undef PH_CLOSE
#undef PH_CLOSE_G
}

// =========================================================================
// GEMM1 (+ fused w2 cvt tail blocks) — R14 exact.
// =========================================================================
__global__ __launch_bounds__(512, 1)
void gemm1_kernel(const __bf16* __restrict__ xg,
                  const __bf16* __restrict__ w1b,
                  const __bf16* __restrict__ w3b,
                  const int* __restrict__ tile_e,
                  const int* __restrict__ tile_r0,
                  const int* __restrict__ meta,
                  __bf16* __restrict__ h,
                  const float* __restrict__ w2src,
                  __bf16* __restrict__ w2dst) {
    const int bid = blockIdx.x;
    if (bid >= G1_GRID) {
        const long i = ((long)(bid - G1_GRID) * 512 + threadIdx.x) * 8;
        if (i < W2_ELEMS) cvt8(w2src, w2dst, i);
        return;
    }
    const int count = meta[0];
    const int bands = (count + 3) >> 2;
    const int live = bands * 112;
    if (bid >= live) return;
    const int w = (bid & 7) * (live >> 3) + (bid >> 3);
    const int q28 = w / 28, r = w % 28;
    const int tile = (q28 >> 2) * 4 + r / 7;
    const int nt = (q28 & 3) * 7 + r % 7;
    if (tile >= count) return;
    const int e = tile_e[tile];
    const int row0 = tile_r0[tile];

    __shared__ __align__(16) __bf16 Ash[2][2][8192];
    __shared__ __align__(16) __bf16 Bsh[2][2][8192];

    const int tid = threadIdx.x;
    const int wave = tid >> 6, lane = tid & 63;
    const int wm = wave >> 2, wn = wave & 3;
    const int fr = lane & 15, fg = lane >> 4;

    const __bf16* srcA[2][2];
    const __bf16* srcB[2][2];
#pragma unroll
    for (int half = 0; half < 2; ++half)
#pragma unroll
        for (int j = 0; j < 2; ++j) {
            const int c = tid + j * 512;
            srcA[half][j] = xg + (long)(row0 + half * 128 + chunk_row(c)) * D_DIM + chunk_col(c);
            const int rb = half * 128 + chunk_row(c);
            const int blk = rb >> 4;
            const int f = nt * 128 + (blk >> 1) * 16 + (rb & 15);
            srcB[half][j] = ((blk & 1) ? w3b : w1b) + ((long)e * F_DIM + f) * D_DIM + chunk_col(c);
        }

    const int abase = fr * 32 + ((fg * 8) ^ ((fr & 8) << 1));
    f32x4 acc[8][4] = {};

    moe_pipeline<16>(srcA, srcB, Ash, Bsh, wave, abase, wm, wn >> 1, wn & 1, acc);

#pragma unroll
    for (int mi = 0; mi < 8; ++mi) {
#pragma unroll
        for (int reg = 0; reg < 4; ++reg) {
            const int lm = wm * 128 + mi * 16 + fg * 4 + reg;
            const long hrow = (long)(row0 + lm) * F_DIM;
#pragma unroll
            for (int b = 0; b < 2; ++b) {
                const float g = acc[mi][2 * b][reg];
                const float u = acc[mi][2 * b + 1][reg];
                const float s = g / (1.f + __expf(-g));
                h[hrow + nt * 128 + (wn * 2 + b) * 16 + fr] = (__bf16)(s * u);
            }
        }
    }
}

// =========================================================================
// GEMM2 (split-K x2, R9 exact): h[256 rows, F-half] x w2[e]^T [256 d] -> partial
// =========================================================================
__global__ __launch_bounds__(512, 1)
void gemm2_kernel(const __bf16* __restrict__ hb,
                  const __bf16* __restrict__ w2b,
                  const int* __restrict__ tile_e,
                  const int* __restrict__ tile_r0,
                  const int* __restrict__ meta,
                  __bf16* __restrict__ o2p) {
    const int count = meta[0];
    const int bands = (count + 3) >> 2;
    const int live = bands * 32;
    const int bid = blockIdx.x;
    if (bid >= live) return;
    const int w = (bid & 7) * (live >> 3) + (bid >> 3);
    const int band = w >> 5, s = w & 31;
    const int tile = band * 4 + (s >> 3);
    const int nt = s & 3, ks = (s >> 2) & 1;
    if (tile >= count) return;
    const int e = tile_e[tile];
    const int row0 = tile_r0[tile];

    __shared__ __align__(16) __bf16 Ash[2][2][8192];
    __shared__ __align__(16) __bf16 Bsh[2][2][8192];

    const int tid = threadIdx.x;
    const int wave = tid >> 6, lane = tid & 63;
    const int wm = wave >> 2, wn = wave & 3;
    const int fr = lane & 15, fg = lane >> 4;
    const int kofs = ks * (F_DIM / 2);

    const __bf16* srcA[2][2];
    const __bf16* srcB[2][2];
#pragma unroll
    for (int half = 0; half < 2; ++half)
#pragma unroll
        for (int j = 0; j < 2; ++j) {
            const int c = tid + j * 512;
            srcA[half][j] = hb + (long)(row0 + half * 128 + chunk_row(c)) * F_DIM + kofs + chunk_col(c);
            const int rb = half * 128 + chunk_row(c);
            srcB[half][j] = w2b + ((long)e * D_DIM + nt * 256 + rb) * F_DIM + kofs + chunk_col(c);
        }

    const int abase = fr * 32 + ((fg * 8) ^ ((fr & 8) << 1));
    f32x4 acc[8][4] = {};

    moe_pipeline<28>(srcA, srcB, Ash, Bsh, wave, abase, wm, wn >> 1, wn & 1, acc);

    __bf16* ps = o2p + (long)ks * PROWS_PAD * D_DIM;
#pragma unroll
    for (int mi = 0; mi < 8; ++mi) {
#pragma unroll
        for (int reg = 0; reg < 4; ++reg) {
            const int lm = wm * 128 + mi * 16 + fg * 4 + reg;
            const long obase = (long)(row0 + lm) * D_DIM + nt * 256 + wn * 64 + fr;
#pragma unroll
            for (int ni = 0; ni < 4; ++ni)
                ps[obase + ni * 16] = (__bf16)acc[mi][ni][reg];
        }
    }
}

// -------- combine: out[t] = sum_s ( w0*ps[s][r0] + w1*ps[s][r1] ) --------
__global__ void combine_kernel(const __bf16* __restrict__ o2p, const int* __restrict__ rowOf,
                               const float* __restrict__ ewgt, float* __restrict__ out) {
    const int idx = blockIdx.x * blockDim.x + threadIdx.x;  // T * D/8
    const int t = idx >> 7;
    const int j = (idx & 127) * 8;
    const long r0 = rowOf[2 * t], r1 = rowOf[2 * t + 1];
    const float w0 = ewgt[2 * t], w1 = ewgt[2 * t + 1];
    float r[8] = {0, 0, 0, 0, 0, 0, 0, 0};
#pragma unroll
    for (int s = 0; s < 2; ++s) {
        const bf16x8 a = *(const bf16x8*)(o2p + ((long)s * PROWS_PAD + r0) * D_DIM + j);
        const bf16x8 b = *(const bf16x8*)(o2p + ((long)s * PROWS_PAD + r1) * D_DIM + j);
#pragma unroll
        for (int q = 0; q < 8; ++q) r[q] += w0 * (float)a[q] + w1 * (float)b[q];
    }
    float4* ob = (float4*)(out + (long)t * D_DIM + j);
    ob[0] = make_float4(r[0], r[1], r[2], r[3]);
    ob[1] = make_float4(r[4], r[5], r[6], r[7]);
}

// =========================================================================
extern "C" void kernel_launch(void* const* d_in, const int* in_sizes, int n_in,
                              void* d_out, int out_size, void* d_ws, size_t ws_size,
                              hipStream_t stream) {
    const float* x  = (const float*)d_in[0];
    const float* w1 = (const float*)d_in[1];
    const float* w3 = (const float*)d_in[2];
    const float* w2 = (const float*)d_in[3];
    const float* rl = (const float*)d_in[4];
    float* out = (float*)d_out;

    char* ws = (char*)d_ws;
    size_t off = 0;
    auto alloc = [&](size_t bytes) {
        void* p = ws + off;
        off += (bytes + 255) & ~(size_t)255;
        return p;
    };
    __bf16* xg   = (__bf16*)alloc((size_t)PROWS_PAD * D_DIM * 2);        // 37.7 MB
    __bf16* w1b  = (__bf16*)alloc((size_t)E_EXP * F_DIM * D_DIM * 2);    // 58.7 MB
    __bf16* w3b  = (__bf16*)alloc((size_t)E_EXP * F_DIM * D_DIM * 2);    // 58.7 MB
    __bf16* hbuf = (__bf16*)alloc((size_t)PROWS_PAD * F_DIM * 2);        // 132.1 MB
    int*   tokOf = (int*)alloc(PROWS_PAD * 4);
    int*   rowOf = (int*)alloc(NROW * 4);
    int*   eidx  = (int*)alloc(NROW * 4);
    float* ewgt  = (float*)alloc(NROW * 4);
    int*   cnt1  = (int*)alloc(64);
    int*   cnt2  = (int*)alloc(64);
    int*   pofs  = (int*)alloc(64);
    int*   tileE = (int*)alloc(MAXTILES * 4 + 64);
    int*   tileR = (int*)alloc(MAXTILES * 4 + 64);
    int*   meta  = (int*)alloc(64);

    const size_t W2B_BYTES = (size_t)W2_ELEMS * 2;                       // 58.7 MB
    const size_t front = off;
    // Fused path (ws >= front + 58.7MB): w2b fresh & disjoint -> w2 cvt runs
    // as gemm1 tail blocks, overlapped. o2p x2 (75.5MB) aliases dead
    // [xg|w1b-prefix..]. Fallback: exact R9 serial layout.
    const bool fused = (ws_size >= front + W2B_BYTES);
    __bf16* w2b;
    __bf16* o2p;
    if (fused) {
        w2b = (__bf16*)alloc(W2B_BYTES);
        o2p = (__bf16*)ws;
    } else {
        w2b = (__bf16*)ws;
        o2p = (__bf16*)(ws + W2B_BYTES);
    }

    hipMemsetAsync(cnt1, 0, 64, stream);
    hipMemsetAsync(cnt2, 0, 64, stream);
    hipMemsetAsync(tokOf, 0xFF, PROWS_PAD * 4, stream);

    route_kernel<<<T_TOK / 256, 256, 0, stream>>>(rl, cnt1, eidx, ewgt);
    scan_kernel<<<1, 64, 0, stream>>>(cnt1, pofs);
    tiles_kernel<<<1, 64, 0, stream>>>(pofs, tileE, tileR, meta);
    assign_kernel<<<T_TOK / 256, 256, 0, stream>>>(eidx, pofs, cnt2, tokOf, rowOf);

    // merged prep: x gather + w1 cvt + w3 cvt, one launch
    prep_kernel<<<GATH_BLOCKS + 2 * W13_BLOCKS, 256, 0, stream>>>(
        x, tokOf, xg, w1, w1b, w3, w3b);

    if (fused) {
        gemm1_kernel<<<G1_GRID + W2_CVT_BLOCKS, 512, 0, stream>>>(
            xg, w1b, w3b, tileE, tileR, meta, hbuf, w2, w2b);
    } else {
        gemm1_kernel<<<G1_GRID, 512, 0, stream>>>(
            xg, w1b, w3b, tileE, tileR, meta, hbuf, w2, w2b);
        cvt_kernel<<<(int)(W2_ELEMS / 8 / 256), 256, 0, stream>>>(w2, w2b, W2_ELEMS);
    }

    gemm2_kernel<<<MAXBANDS * 32, 512, 0, stream>>>(hbuf, w2b, tileE, tileR, meta, o2p);

    combine_kernel<<<T_TOK * (D_DIM / 8) / 256, 256, 0, stream>>>(o2p, rowOf, ewgt, out);
}